// Round 16
// baseline (147.726 us; speedup 1.0000x reference)
//
#include <hip/hip_runtime.h>
#include <stdint.h>

#define N_SPK 2048
#define M_UTT 16
#define D_EMB 512
#define NM (N_SPK * M_UTT)
#define FP8_SCALE 16.0f   // quantization scale for fp8 operands (1/256 folded into w)
#define NBX 256           // utterance tiles; 16 blocks (by) contribute per bx

typedef __attribute__((ext_vector_type(4))) float f32x4;
typedef __attribute__((ext_vector_type(4))) int   i32x4;
typedef __attribute__((ext_vector_type(8))) int   i32x8;

__device__ __forceinline__ void async_copy16(const void* g, void* l) {
    __builtin_amdgcn_global_load_lds(
        (const __attribute__((address_space(1))) unsigned int*)g,
        (__attribute__((address_space(3))) unsigned int*)l,
        16, 0, 0);
}

// read one 32B (K=128) MFMA fragment from swizzled LDS: granule 2q of row r at
// slot s0 = 2q ^ (r&7), granule 2q+1 at s0^1. base points at the 128B row.
__device__ __forceinline__ i32x8 ld_frag(const unsigned char* base, int s0) {
    i32x4 lo = *(const i32x4*)(base + s0 * 16);
    i32x4 hi = *(const i32x4*)(base + (s0 ^ 1) * 16);
    return __builtin_shufflevector(lo, hi, 0, 1, 2, 3, 4, 5, 6, 7);
}

// ---------------------------------------------------------------------------
// Kernel A: per-speaker prep, ROUND-16 float4 version.
// Thread t owns dim-quad u=t&127 (dims 4u..4u+3) for m-half half=t>>7
// (8 utterances). 8x dwordx4 loads (1KB/wave-instr, the coalescing sweet
// spot) vs the old 16x dwordx2. Cross-half ss combine via 4KB LDS. Packed
// red[16][132] float2 -> LDS ~21KB (was 34KB). dterm math unchanged
// (fp32-exact path); fp8 outputs written as packed 4B words.
// Zeroes colsum/out and (block 0) the 256 per-bx tickets when present.
// ---------------------------------------------------------------------------
__global__ __launch_bounds__(256) void prep_kernel(
    const float* __restrict__ V, const float* __restrict__ wp,
    const float* __restrict__ bp, unsigned char* __restrict__ Cn8,
    unsigned char* __restrict__ vn8, float* __restrict__ dterm,
    float* __restrict__ colsum, float* __restrict__ out,
    int* __restrict__ done)
{
    const int spk = blockIdx.x, t = threadIdx.x;
    const int wave = t >> 6, lane = t & 63;
    const int u = t & 127;      // dim-quad index: dims 4u..4u+3
    const int half = t >> 7;    // utterance half: m = half*8 + mm
    const float4* vb4 = (const float4*)(V + (size_t)spk * (M_UTT * D_EMB)); // [16][128]

    __shared__ __align__(16) float4 ssh[2][128];      // per-half ss partials (4KB)
    __shared__ __align__(16) float2 red[M_UTT][132];  // {sv,vv} per (m,u) +pad (~17KB)
    __shared__ float red2[32];    // rows 0..15 sv, 16..31 vv
    __shared__ float invs[M_UTT];
    __shared__ float wred[4];

    // folded zeroing of colsum + out + per-bx tickets
    if (spk < 128) colsum[spk * 256 + t] = 0.f;
    if (spk == 0) {
        if (done) done[t] = 0;
        if (t == 0) out[0] = 0.f;
    }

    // ---- single global read pass: 8 float4 per thread ----
    float4 p4[8];
#pragma unroll
    for (int mm = 0; mm < 8; ++mm) p4[mm] = vb4[(half * 8 + mm) * 128 + u];

    float4 s4 = make_float4(0.f, 0.f, 0.f, 0.f);
#pragma unroll
    for (int mm = 0; mm < 8; ++mm) {
        s4.x += p4[mm].x; s4.y += p4[mm].y; s4.z += p4[mm].z; s4.w += p4[mm].w;
    }
    ssh[half][u] = s4;
    __syncthreads();
    const float4 o4 = ssh[half ^ 1][u];
    const float4 ss4 = make_float4(s4.x + o4.x, s4.y + o4.y, s4.z + o4.z, s4.w + o4.w);

    // ||ssum||^2: every thread's quad-dot (each u counted twice across halves)
    float c = ss4.x * ss4.x + ss4.y * ss4.y + ss4.z * ss4.z + ss4.w * ss4.w;
#pragma unroll
    for (int off = 32; off > 0; off >>= 1) c += __shfl_xor(c, off);
    if (lane == 0) wred[wave] = c;

    // per-utterance partials -> LDS (packed sv,vv), this thread's 8 m only
#pragma unroll
    for (int mm = 0; mm < 8; ++mm) {
        const float sv = ss4.x * p4[mm].x + ss4.y * p4[mm].y
                       + ss4.z * p4[mm].z + ss4.w * p4[mm].w;
        const float vv = p4[mm].x * p4[mm].x + p4[mm].y * p4[mm].y
                       + p4[mm].z * p4[mm].z + p4[mm].w * p4[mm].w;
        red[half * 8 + mm][u] = make_float2(sv, vv);
    }
    __syncthreads();
    const float cn2 = (wred[0] + wred[1] + wred[2] + wred[3]) * 0.5f; // halves dup

    // ---- batched row reduction: 16 threads per row, 4 float4 each ----
    {
        const int r = t >> 4, s = t & 15;
        const float4* rp = (const float4*)red;   // row stride = 66 float4
        float sv = 0.f, vvs = 0.f;
#pragma unroll
        for (int k = 0; k < 4; ++k) {
            float4 q = rp[r * 66 + s + 16 * k];  // {sv0,vv0,sv1,vv1}
            sv  += q.x + q.z;
            vvs += q.y + q.w;
        }
        sv  += __shfl_xor(sv, 1);  vvs += __shfl_xor(vvs, 1);
        sv  += __shfl_xor(sv, 2);  vvs += __shfl_xor(vvs, 2);
        sv  += __shfl_xor(sv, 4);  vvs += __shfl_xor(vvs, 4);
        sv  += __shfl_xor(sv, 8);  vvs += __shfl_xor(vvs, 8);
        if (s == 0) { red2[r] = sv; red2[r + 16] = vvs; }
    }
    __syncthreads();

    // ---- per-utterance scalars (fp32-exact leave-one-out sims) ----
    if (t < M_UTT) {
        const float sv = red2[t], vv = red2[t + 16];
        const float cc = cn2 - 2.f * sv + vv;      // ||ssum - v||^2
        const float cv = sv - vv;                  // <ssum - v, v>
        const float dc = fmaxf(sqrtf(fmaxf(cc, 0.f)) * (1.f / (M_UTT - 1)), 1e-8f) * (M_UTT - 1);
        const float dv = fmaxf(sqrtf(vv), 1e-8f);
        dterm[spk * M_UTT + t] = (*wp) * (cv / (dc * dv)) + (*bp);
        invs[t] = FP8_SCALE / dv;
    }
    __syncthreads();

    // ---- fp8 outputs (x16 scale), packed 4B words ----
    const float cs = FP8_SCALE / (M_UTT * fmaxf(sqrtf(cn2) * (1.f / M_UTT), 1e-8f));
    if (half == 0) {
        int lo = __builtin_amdgcn_cvt_pk_fp8_f32(ss4.x * cs, ss4.y * cs, 0, false);
        int hi = __builtin_amdgcn_cvt_pk_fp8_f32(ss4.z * cs, ss4.w * cs, 0, false);
        ((unsigned int*)(Cn8 + (size_t)spk * D_EMB))[u] =
            ((unsigned int)lo & 0xffffu) | ((unsigned int)hi << 16);
    }
#pragma unroll
    for (int mm = 0; mm < 8; ++mm) {
        const int m = half * 8 + mm;
        const float iv = invs[m];
        int lo = __builtin_amdgcn_cvt_pk_fp8_f32(p4[mm].x * iv, p4[mm].y * iv, 0, false);
        int hi = __builtin_amdgcn_cvt_pk_fp8_f32(p4[mm].z * iv, p4[mm].w * iv, 0, false);
        ((unsigned int*)(vn8 + ((size_t)(spk * M_UTT + m)) * D_EMB))[u] =
            ((unsigned int)lo & 0xffffu) | ((unsigned int)hi << 16);
    }
}

// ---------------------------------------------------------------------------
// Kernel B: MX-scaled fp8 GEMM fused with exp(w'S+b), masking, col-reduce,
// + PER-BX parallel fused finisher (round-15 champion, verified 52.0us with
// finisher hidden). Round-16 micro-opt: log2e pre-folded into wgt/bsc ->
// exp2f (saves one v_mul per element; algebraically exact).
// GEMM core = round-5 best: single-buffer 33KB LDS, serial K-loop,
// launch_bounds(256,2) -> 4 blocks/CU (the VGPR-88 occupancy optimum).
// Coherence chain (verified absmax 0, r14/r15): colsum atomics -> vmcnt(0)
// -> per-bx ticket -> atomicAdd(p,0.f) coherent re-read. Non-blocking.
// XCD remap (T1): confirmed -5.4x FETCH. Swizzle: granule g of row r at
// slot g^(r&7), 128B rows.
// ---------------------------------------------------------------------------
__global__ __launch_bounds__(256, 2) void gemm_kernel(
    const unsigned char* __restrict__ Cn8, const unsigned char* __restrict__ vn8,
    const float* __restrict__ wp, const float* __restrict__ bp,
    float* __restrict__ colsum, const float* __restrict__ dterm,
    float* __restrict__ out, int* __restrict__ done)
{
    __shared__ __align__(16) unsigned char As[128 * 128];  // 16KB single buffer
    __shared__ __align__(16) unsigned char Bs[128 * 128];  // 16KB single buffer
    __shared__ float csum[128];
    __shared__ int lastFlag;

    const int tid = threadIdx.x;
    const int w = tid >> 6, l = tid & 63;

    // XCD-aware remap: dispatch-linear id p round-robins across 8 XCDs.
    const int p_lin = blockIdx.x + 16 * blockIdx.y;     // [0, 4096)
    const int L_log = (p_lin & 7) * 512 + (p_lin >> 3); // bijective (4096 % 8 == 0)
    const int by = L_log & 15;    // speaker tile   [0,16)
    const int bx = L_log >> 4;    // utterance tile [0,256)

    const float LOG2E = 1.44269504088896f;
    const float wgt2 = (*wp) * (1.f / (FP8_SCALE * FP8_SCALE)) * LOG2E;
    const float bsc2 = (*bp) * LOG2E;

    if (tid < 128) csum[tid] = 0.f;

    // ---- staging geometry: wave w covers rows w*32..w*32+31 of both tiles.
    const int r_l = l >> 3, sl8 = l & 7;
    const int g = sl8 ^ r_l;
    const unsigned char* Ab = Cn8 + (size_t)(by * 128 + w * 32 + r_l) * D_EMB + g * 16;
    const unsigned char* Bb = vn8 + (size_t)(bx * 128 + w * 32 + r_l) * D_EMB + g * 16;
    unsigned char* AsW = As + (w * 32) * 128;
    unsigned char* BsW = Bs + (w * 32) * 128;

    // ---- compute geometry: 2x2 wave grid, each wave 64x64 = 4x4 MFMA (K=128)
    const int wm = w & 1, wn = w >> 1;
    const int l16 = l & 15, q = l >> 4;
    const int s0 = (2 * q) ^ (l & 7);
    const unsigned char* Ard = As + (wm * 64 + l16) * 128;
    const unsigned char* Brd = Bs + (wn * 64 + l16) * 128;

    f32x4 acc[4][4];
    const f32x4 z = {0.f, 0.f, 0.f, 0.f};
#pragma unroll
    for (int i = 0; i < 4; ++i)
#pragma unroll
        for (int j = 0; j < 4; ++j) acc[i][j] = z;

    // ---- simple serial K loop: 4 tiles of BK=128, cross-block TLP hides it
#pragma unroll
    for (int t = 0; t < 4; ++t) {
        const int kk = t * 128;
#pragma unroll
        for (int i = 0; i < 4; ++i) {
            async_copy16(Ab + i * 4096 + kk, AsW + i * 1024);
            async_copy16(Bb + i * 4096 + kk, BsW + i * 1024);
        }
        __syncthreads();   // vmcnt(0) drain + barrier: tile ready
        i32x8 bfr[4];
#pragma unroll
        for (int j = 0; j < 4; ++j) bfr[j] = ld_frag(Brd + j * 2048, s0);
#pragma unroll
        for (int i = 0; i < 4; ++i) {
            i32x8 af = ld_frag(Ard + i * 2048, s0);
#pragma unroll
            for (int j = 0; j < 4; ++j)
                acc[i][j] = __builtin_amdgcn_mfma_scale_f32_16x16x128_f8f6f4(
                    af, bfr[j], acc[i][j], 0, 0, 0, 0x7F7F7F7F, 0, 0x7F7F7F7F);
        }
        __syncthreads();   // all waves done reading before next stage overwrites
    }

    // epilogue: e = exp2(w2*dot+b2), zero same-speaker entries, reduce rows.
    // C/D layout (shape-determined): row = q*4 + r, col = l16.
    const int rowg0 = by * 128 + wm * 64 + q * 4;
    const int colg0 = bx * 128 + wn * 64 + l16;
#pragma unroll
    for (int j = 0; j < 4; ++j) {
        const int colg = colg0 + j * 16;
        const int cspk = colg >> 4;       // speaker owning this column
        float p = 0.f;
#pragma unroll
        for (int i = 0; i < 4; ++i) {
            const int rowg = rowg0 + i * 16;
#pragma unroll
            for (int r = 0; r < 4; ++r) {
                float e = exp2f(wgt2 * acc[i][j][r] + bsc2);
                p += (rowg + r == cspk) ? 0.f : e;
            }
        }
        p += __shfl_xor(p, 16);
        p += __shfl_xor(p, 32);
        if (q == 0) atomicAdd(&csum[wn * 64 + j * 16 + l16], p);
    }
    __syncthreads();
    if (tid < 128) atomicAdd(&colsum[bx * 128 + tid], csum[tid]);

    // ---- per-bx fused finisher: 16th arrival finishes its 128 columns ----
    if (done != nullptr) {
        asm volatile("s_waitcnt vmcnt(0)" ::: "memory");  // own atomics at L2
        __syncthreads();                                   // ...for ALL threads
        if (tid == 0)
            lastFlag = (atomicAdd(&done[bx], 1) == 15);
        __syncthreads();
        if (lastFlag) {
            float local = 0.f;
            if (tid < 128) {
                const int j = bx * 128 + tid;
                const float td = dterm[j];
                const float cs2 = atomicAdd(&colsum[j], 0.0f);  // coherent read
                local = logf(cs2 + __expf(td)) - td;
            }
#pragma unroll
            for (int off = 32; off > 0; off >>= 1) local += __shfl_xor(local, off);
            if (l == 0) csum[w] = local;   // reuse csum as wave scratch
            __syncthreads();
            if (tid == 0) atomicAdd(out, csum[0] + csum[1] + csum[2] + csum[3]);
        }
    }
}

// ---------------------------------------------------------------------------
// Kernel C (fallback when workspace lacks ticket space):
// L_j = -dterm_j + log(colsum_j + exp(dterm_j)); sum -> out[0]
// ---------------------------------------------------------------------------
__global__ __launch_bounds__(256) void finish_kernel(
    const float* __restrict__ dterm, const float* __restrict__ colsum,
    float* __restrict__ out)
{
    const int idx = blockIdx.x * 256 + threadIdx.x;
    const int stride = gridDim.x * 256;
    float local = 0.f;
    for (int j = idx; j < NM; j += stride) {
        float t = dterm[j];
        local += logf(colsum[j] + __expf(t)) - t;
    }
#pragma unroll
    for (int off = 32; off > 0; off >>= 1) local += __shfl_xor(local, off);
    __shared__ float wr[4];
    const int wave = threadIdx.x >> 6, lane = threadIdx.x & 63;
    if (lane == 0) wr[wave] = local;
    __syncthreads();
    if (threadIdx.x == 0) atomicAdd(out, wr[0] + wr[1] + wr[2] + wr[3]);
}

extern "C" void kernel_launch(void* const* d_in, const int* in_sizes, int n_in,
                              void* d_out, int out_size, void* d_ws, size_t ws_size,
                              hipStream_t stream) {
    const float* V  = (const float*)d_in[0];
    const float* wp = (const float*)d_in[1];
    const float* bp = (const float*)d_in[2];

    char* ws = (char*)d_ws;
    unsigned char* Cn8 = (unsigned char*)ws;                        //  1 MB [2048][512] fp8
    unsigned char* vn8 = (unsigned char*)(ws + ((size_t)1 << 20));  // 16 MB [32768][512] fp8
    float* dterm  = (float*)(ws + ((size_t)17 << 20));              // 128 KB
    float* colsum = dterm + NM;                                     // 128 KB
    float* out    = (float*)d_out;

    // per-bx ticket array past the legacy layout -- ONLY if ws has room.
    const size_t legacy_end = ((size_t)17 << 20) + (size_t)2 * NM * sizeof(float);
    int* done = (ws_size >= legacy_end + NBX * sizeof(int))
                    ? (int*)(ws + legacy_end) : nullptr;

    prep_kernel<<<N_SPK, 256, 0, stream>>>(V, wp, bp, Cn8, vn8, dterm, colsum, out, done);
    gemm_kernel<<<dim3(16, 256), 256, 0, stream>>>(Cn8, vn8, wp, bp, colsum, dterm, out, done);
    if (done == nullptr)
        finish_kernel<<<64, 256, 0, stream>>>(dterm, colsum, out);
}

// Round 17
// 143.066 us; speedup vs baseline: 1.0326x; 1.0326x over previous
//
#include <hip/hip_runtime.h>
#include <stdint.h>

#define N_SPK 2048
#define M_UTT 16
#define D_EMB 512
#define NM (N_SPK * M_UTT)
#define FP8_SCALE 16.0f   // quantization scale for fp8 operands (1/256 folded into w)
#define NBX 256           // utterance tiles; 16 blocks (by) contribute per bx

typedef __attribute__((ext_vector_type(4))) float f32x4;
typedef __attribute__((ext_vector_type(4))) int   i32x4;
typedef __attribute__((ext_vector_type(8))) int   i32x8;

__device__ __forceinline__ void async_copy16(const void* g, void* l) {
    __builtin_amdgcn_global_load_lds(
        (const __attribute__((address_space(1))) unsigned int*)g,
        (__attribute__((address_space(3))) unsigned int*)l,
        16, 0, 0);
}

// read one 32B (K=128) MFMA fragment from swizzled LDS: granule 2q of row r at
// slot s0 = 2q ^ (r&7), granule 2q+1 at s0^1. base points at the 128B row.
__device__ __forceinline__ i32x8 ld_frag(const unsigned char* base, int s0) {
    i32x4 lo = *(const i32x4*)(base + s0 * 16);
    i32x4 hi = *(const i32x4*)(base + (s0 ^ 1) * 16);
    return __builtin_shufflevector(lo, hi, 0, 1, 2, 3, 4, 5, 6, 7);
}

// ---------------------------------------------------------------------------
// Kernel A: per-speaker prep, float4 version (round-16, kept: residual was
// neutral-to-better). Thread t owns dim-quad u=t&127 for m-half half=t>>7.
// 8x dwordx4 loads; cross-half ss combine via 4KB LDS; packed red float2;
// packed 4B fp8 writes. Zeroes colsum/out and per-bx tickets when present.
// ---------------------------------------------------------------------------
__global__ __launch_bounds__(256) void prep_kernel(
    const float* __restrict__ V, const float* __restrict__ wp,
    const float* __restrict__ bp, unsigned char* __restrict__ Cn8,
    unsigned char* __restrict__ vn8, float* __restrict__ dterm,
    float* __restrict__ colsum, float* __restrict__ out,
    int* __restrict__ done)
{
    const int spk = blockIdx.x, t = threadIdx.x;
    const int wave = t >> 6, lane = t & 63;
    const int u = t & 127;      // dim-quad index: dims 4u..4u+3
    const int half = t >> 7;    // utterance half: m = half*8 + mm
    const float4* vb4 = (const float4*)(V + (size_t)spk * (M_UTT * D_EMB)); // [16][128]

    __shared__ __align__(16) float4 ssh[2][128];      // per-half ss partials (4KB)
    __shared__ __align__(16) float2 red[M_UTT][132];  // {sv,vv} per (m,u) +pad (~17KB)
    __shared__ float red2[32];    // rows 0..15 sv, 16..31 vv
    __shared__ float invs[M_UTT];
    __shared__ float wred[4];

    // folded zeroing of colsum + out + per-bx tickets
    if (spk < 128) colsum[spk * 256 + t] = 0.f;
    if (spk == 0) {
        if (done) done[t] = 0;
        if (t == 0) out[0] = 0.f;
    }

    // ---- single global read pass: 8 float4 per thread ----
    float4 p4[8];
#pragma unroll
    for (int mm = 0; mm < 8; ++mm) p4[mm] = vb4[(half * 8 + mm) * 128 + u];

    float4 s4 = make_float4(0.f, 0.f, 0.f, 0.f);
#pragma unroll
    for (int mm = 0; mm < 8; ++mm) {
        s4.x += p4[mm].x; s4.y += p4[mm].y; s4.z += p4[mm].z; s4.w += p4[mm].w;
    }
    ssh[half][u] = s4;
    __syncthreads();
    const float4 o4 = ssh[half ^ 1][u];
    const float4 ss4 = make_float4(s4.x + o4.x, s4.y + o4.y, s4.z + o4.z, s4.w + o4.w);

    // ||ssum||^2: every thread's quad-dot (each u counted twice across halves)
    float c = ss4.x * ss4.x + ss4.y * ss4.y + ss4.z * ss4.z + ss4.w * ss4.w;
#pragma unroll
    for (int off = 32; off > 0; off >>= 1) c += __shfl_xor(c, off);
    if (lane == 0) wred[wave] = c;

    // per-utterance partials -> LDS (packed sv,vv), this thread's 8 m only
#pragma unroll
    for (int mm = 0; mm < 8; ++mm) {
        const float sv = ss4.x * p4[mm].x + ss4.y * p4[mm].y
                       + ss4.z * p4[mm].z + ss4.w * p4[mm].w;
        const float vv = p4[mm].x * p4[mm].x + p4[mm].y * p4[mm].y
                       + p4[mm].z * p4[mm].z + p4[mm].w * p4[mm].w;
        red[half * 8 + mm][u] = make_float2(sv, vv);
    }
    __syncthreads();
    const float cn2 = (wred[0] + wred[1] + wred[2] + wred[3]) * 0.5f; // halves dup

    // ---- batched row reduction: 16 threads per row, 4 float4 each ----
    {
        const int r = t >> 4, s = t & 15;
        const float4* rp = (const float4*)red;   // row stride = 66 float4
        float sv = 0.f, vvs = 0.f;
#pragma unroll
        for (int k = 0; k < 4; ++k) {
            float4 q = rp[r * 66 + s + 16 * k];  // {sv0,vv0,sv1,vv1}
            sv  += q.x + q.z;
            vvs += q.y + q.w;
        }
        sv  += __shfl_xor(sv, 1);  vvs += __shfl_xor(vvs, 1);
        sv  += __shfl_xor(sv, 2);  vvs += __shfl_xor(vvs, 2);
        sv  += __shfl_xor(sv, 4);  vvs += __shfl_xor(vvs, 4);
        sv  += __shfl_xor(sv, 8);  vvs += __shfl_xor(vvs, 8);
        if (s == 0) { red2[r] = sv; red2[r + 16] = vvs; }
    }
    __syncthreads();

    // ---- per-utterance scalars (fp32-exact leave-one-out sims) ----
    if (t < M_UTT) {
        const float sv = red2[t], vv = red2[t + 16];
        const float cc = cn2 - 2.f * sv + vv;      // ||ssum - v||^2
        const float cv = sv - vv;                  // <ssum - v, v>
        const float dc = fmaxf(sqrtf(fmaxf(cc, 0.f)) * (1.f / (M_UTT - 1)), 1e-8f) * (M_UTT - 1);
        const float dv = fmaxf(sqrtf(vv), 1e-8f);
        dterm[spk * M_UTT + t] = (*wp) * (cv / (dc * dv)) + (*bp);
        invs[t] = FP8_SCALE / dv;
    }
    __syncthreads();

    // ---- fp8 outputs (x16 scale), packed 4B words ----
    const float cs = FP8_SCALE / (M_UTT * fmaxf(sqrtf(cn2) * (1.f / M_UTT), 1e-8f));
    if (half == 0) {
        int lo = __builtin_amdgcn_cvt_pk_fp8_f32(ss4.x * cs, ss4.y * cs, 0, false);
        int hi = __builtin_amdgcn_cvt_pk_fp8_f32(ss4.z * cs, ss4.w * cs, 0, false);
        ((unsigned int*)(Cn8 + (size_t)spk * D_EMB))[u] =
            ((unsigned int)lo & 0xffffu) | ((unsigned int)hi << 16);
    }
#pragma unroll
    for (int mm = 0; mm < 8; ++mm) {
        const int m = half * 8 + mm;
        const float iv = invs[m];
        int lo = __builtin_amdgcn_cvt_pk_fp8_f32(p4[mm].x * iv, p4[mm].y * iv, 0, false);
        int hi = __builtin_amdgcn_cvt_pk_fp8_f32(p4[mm].z * iv, p4[mm].w * iv, 0, false);
        ((unsigned int*)(vn8 + ((size_t)(spk * M_UTT + m)) * D_EMB))[u] =
            ((unsigned int)lo & 0xffffu) | ((unsigned int)hi << 16);
    }
}

// ---------------------------------------------------------------------------
// Kernel B: MX-scaled fp8 GEMM fused with exp(w'S+b), masking, col-reduce,
// + PER-BX parallel fused finisher. EXACT round-15 champion epilogue:
// __expf (bare v_exp_f32), NOT exp2f -- ROUND-16 LESSON: exp2f is the
// precise libm path with range-fixup code; VALUBusy 29->40%, gemm +4us.
// GEMM core = round-5 best: single-buffer 33KB LDS, serial K-loop,
// launch_bounds(256,2) -> 4 blocks/CU (the VGPR-88 occupancy optimum).
// Coherence chain (verified absmax 0, r14/r15): colsum atomics -> vmcnt(0)
// -> per-bx ticket -> atomicAdd(p,0.f) coherent re-read. Non-blocking.
// XCD remap (T1): confirmed -5.4x FETCH. Swizzle: granule g of row r at
// slot g^(r&7), 128B rows.
// ---------------------------------------------------------------------------
__global__ __launch_bounds__(256, 2) void gemm_kernel(
    const unsigned char* __restrict__ Cn8, const unsigned char* __restrict__ vn8,
    const float* __restrict__ wp, const float* __restrict__ bp,
    float* __restrict__ colsum, const float* __restrict__ dterm,
    float* __restrict__ out, int* __restrict__ done)
{
    __shared__ __align__(16) unsigned char As[128 * 128];  // 16KB single buffer
    __shared__ __align__(16) unsigned char Bs[128 * 128];  // 16KB single buffer
    __shared__ float csum[128];
    __shared__ int lastFlag;

    const int tid = threadIdx.x;
    const int w = tid >> 6, l = tid & 63;

    // XCD-aware remap: dispatch-linear id p round-robins across 8 XCDs.
    const int p_lin = blockIdx.x + 16 * blockIdx.y;     // [0, 4096)
    const int L_log = (p_lin & 7) * 512 + (p_lin >> 3); // bijective (4096 % 8 == 0)
    const int by = L_log & 15;    // speaker tile   [0,16)
    const int bx = L_log >> 4;    // utterance tile [0,256)

    const float wgt = (*wp) * (1.f / (FP8_SCALE * FP8_SCALE));
    const float bsc = *bp;

    if (tid < 128) csum[tid] = 0.f;

    // ---- staging geometry: wave w covers rows w*32..w*32+31 of both tiles.
    const int r_l = l >> 3, sl8 = l & 7;
    const int g = sl8 ^ r_l;
    const unsigned char* Ab = Cn8 + (size_t)(by * 128 + w * 32 + r_l) * D_EMB + g * 16;
    const unsigned char* Bb = vn8 + (size_t)(bx * 128 + w * 32 + r_l) * D_EMB + g * 16;
    unsigned char* AsW = As + (w * 32) * 128;
    unsigned char* BsW = Bs + (w * 32) * 128;

    // ---- compute geometry: 2x2 wave grid, each wave 64x64 = 4x4 MFMA (K=128)
    const int wm = w & 1, wn = w >> 1;
    const int l16 = l & 15, q = l >> 4;
    const int s0 = (2 * q) ^ (l & 7);
    const unsigned char* Ard = As + (wm * 64 + l16) * 128;
    const unsigned char* Brd = Bs + (wn * 64 + l16) * 128;

    f32x4 acc[4][4];
    const f32x4 z = {0.f, 0.f, 0.f, 0.f};
#pragma unroll
    for (int i = 0; i < 4; ++i)
#pragma unroll
        for (int j = 0; j < 4; ++j) acc[i][j] = z;

    // ---- simple serial K loop: 4 tiles of BK=128, cross-block TLP hides it
#pragma unroll
    for (int t = 0; t < 4; ++t) {
        const int kk = t * 128;
#pragma unroll
        for (int i = 0; i < 4; ++i) {
            async_copy16(Ab + i * 4096 + kk, AsW + i * 1024);
            async_copy16(Bb + i * 4096 + kk, BsW + i * 1024);
        }
        __syncthreads();   // vmcnt(0) drain + barrier: tile ready
        i32x8 bfr[4];
#pragma unroll
        for (int j = 0; j < 4; ++j) bfr[j] = ld_frag(Brd + j * 2048, s0);
#pragma unroll
        for (int i = 0; i < 4; ++i) {
            i32x8 af = ld_frag(Ard + i * 2048, s0);
#pragma unroll
            for (int j = 0; j < 4; ++j)
                acc[i][j] = __builtin_amdgcn_mfma_scale_f32_16x16x128_f8f6f4(
                    af, bfr[j], acc[i][j], 0, 0, 0, 0x7F7F7F7F, 0, 0x7F7F7F7F);
        }
        __syncthreads();   // all waves done reading before next stage overwrites
    }

    // epilogue: e = exp(w'*dot+b), zero same-speaker entries, reduce over rows.
    // C/D layout (shape-determined): row = q*4 + r, col = l16.
    const int rowg0 = by * 128 + wm * 64 + q * 4;
    const int colg0 = bx * 128 + wn * 64 + l16;
#pragma unroll
    for (int j = 0; j < 4; ++j) {
        const int colg = colg0 + j * 16;
        const int cspk = colg >> 4;       // speaker owning this column
        float p = 0.f;
#pragma unroll
        for (int i = 0; i < 4; ++i) {
            const int rowg = rowg0 + i * 16;
#pragma unroll
            for (int r = 0; r < 4; ++r) {
                float e = __expf(wgt * acc[i][j][r] + bsc);
                p += (rowg + r == cspk) ? 0.f : e;
            }
        }
        p += __shfl_xor(p, 16);
        p += __shfl_xor(p, 32);
        if (q == 0) atomicAdd(&csum[wn * 64 + j * 16 + l16], p);
    }
    __syncthreads();
    if (tid < 128) atomicAdd(&colsum[bx * 128 + tid], csum[tid]);

    // ---- per-bx fused finisher: 16th arrival finishes its 128 columns ----
    if (done != nullptr) {
        asm volatile("s_waitcnt vmcnt(0)" ::: "memory");  // own atomics at L2
        __syncthreads();                                   // ...for ALL threads
        if (tid == 0)
            lastFlag = (atomicAdd(&done[bx], 1) == 15);
        __syncthreads();
        if (lastFlag) {
            float local = 0.f;
            if (tid < 128) {
                const int j = bx * 128 + tid;
                const float td = dterm[j];
                const float cs2 = atomicAdd(&colsum[j], 0.0f);  // coherent read
                local = logf(cs2 + __expf(td)) - td;
            }
#pragma unroll
            for (int off = 32; off > 0; off >>= 1) local += __shfl_xor(local, off);
            if (l == 0) csum[w] = local;   // reuse csum as wave scratch
            __syncthreads();
            if (tid == 0) atomicAdd(out, csum[0] + csum[1] + csum[2] + csum[3]);
        }
    }
}

// ---------------------------------------------------------------------------
// Kernel C (fallback when workspace lacks ticket space):
// L_j = -dterm_j + log(colsum_j + exp(dterm_j)); sum -> out[0]
// ---------------------------------------------------------------------------
__global__ __launch_bounds__(256) void finish_kernel(
    const float* __restrict__ dterm, const float* __restrict__ colsum,
    float* __restrict__ out)
{
    const int idx = blockIdx.x * 256 + threadIdx.x;
    const int stride = gridDim.x * 256;
    float local = 0.f;
    for (int j = idx; j < NM; j += stride) {
        float t = dterm[j];
        local += logf(colsum[j] + __expf(t)) - t;
    }
#pragma unroll
    for (int off = 32; off > 0; off >>= 1) local += __shfl_xor(local, off);
    __shared__ float wr[4];
    const int wave = threadIdx.x >> 6, lane = threadIdx.x & 63;
    if (lane == 0) wr[wave] = local;
    __syncthreads();
    if (threadIdx.x == 0) atomicAdd(out, wr[0] + wr[1] + wr[2] + wr[3]);
}

extern "C" void kernel_launch(void* const* d_in, const int* in_sizes, int n_in,
                              void* d_out, int out_size, void* d_ws, size_t ws_size,
                              hipStream_t stream) {
    const float* V  = (const float*)d_in[0];
    const float* wp = (const float*)d_in[1];
    const float* bp = (const float*)d_in[2];

    char* ws = (char*)d_ws;
    unsigned char* Cn8 = (unsigned char*)ws;                        //  1 MB [2048][512] fp8
    unsigned char* vn8 = (unsigned char*)(ws + ((size_t)1 << 20));  // 16 MB [32768][512] fp8
    float* dterm  = (float*)(ws + ((size_t)17 << 20));              // 128 KB
    float* colsum = dterm + NM;                                     // 128 KB
    float* out    = (float*)d_out;

    // per-bx ticket array past the legacy layout -- ONLY if ws has room.
    const size_t legacy_end = ((size_t)17 << 20) + (size_t)2 * NM * sizeof(float);
    int* done = (ws_size >= legacy_end + NBX * sizeof(int))
                    ? (int*)(ws + legacy_end) : nullptr;

    prep_kernel<<<N_SPK, 256, 0, stream>>>(V, wp, bp, Cn8, vn8, dterm, colsum, out, done);
    gemm_kernel<<<dim3(16, 256), 256, 0, stream>>>(Cn8, vn8, wp, bp, colsum, dterm, out, done);
    if (done == nullptr)
        finish_kernel<<<64, 256, 0, stream>>>(dterm, colsum, out);
}